// Round 3
// baseline (69.546 us; speedup 1.0000x reference)
//
#include <hip/hip_runtime.h>

// Problem: out[r][c] = in[r][c] * weight[c][c] + bias[c]
// B = 8192 rows, N = 4096 cols, all float32.
// Pure memory-bound elementwise op: 128 MiB read + 128 MiB write.
//
// Thread t owns column-quad j = t & 1023 and rows r = (t >> 10) + 512*k,
// k = 0..15. diag/bias are loop-invariant -> registers; hot loop is
// 1 load + 1 store per 16 B (was 3 loads + 1 store in round 1).
// Nontemporal hints: in/out are stream-once; keep diag/bias in cache.

#define NCOL 4096
#define NROW 8192
#define QCOL (NCOL / 4)          // 1024 column quads
#define ROWGROUPS 512            // 524288 threads / 1024 quad-cols
#define ITERS (NROW / ROWGROUPS) // 16 rows per thread

typedef float f4 __attribute__((ext_vector_type(4)));  // plain vector type
                                                       // (nontemporal builtins
                                                       // reject HIP_vector_type)

__global__ __launch_bounds__(256)
void extract_diag_kernel(const float* __restrict__ w, float* __restrict__ d) {
    int i = blockIdx.x * blockDim.x + threadIdx.x;
    if (i < NCOL) {
        d[i] = w[(size_t)i * (NCOL + 1)];   // w[i*N + i]
    }
}

__global__ __launch_bounds__(256)
void scale_bias_kernel(const f4* __restrict__ in,
                       const f4* __restrict__ diag4,
                       const f4* __restrict__ bias4,
                       f4* __restrict__ out) {
    const int t  = blockIdx.x * blockDim.x + threadIdx.x;  // 0..524287
    const int j  = t & (QCOL - 1);                         // fixed column quad
    const int r0 = t >> 10;                                // base row 0..511

    const f4 d = diag4[j];   // loop-invariant, L2-resident (16 KiB)
    const f4 b = bias4[j];

    size_t idx = (size_t)r0 * QCOL + j;
#pragma unroll
    for (int k = 0; k < ITERS; ++k) {
        f4 x = __builtin_nontemporal_load(&in[idx]);
        f4 o;
        o.x = fmaf(x.x, d.x, b.x);
        o.y = fmaf(x.y, d.y, b.y);
        o.z = fmaf(x.z, d.z, b.z);
        o.w = fmaf(x.w, d.w, b.w);
        __builtin_nontemporal_store(o, &out[idx]);
        idx += (size_t)ROWGROUPS * QCOL;   // advance 512 rows
    }
}

extern "C" void kernel_launch(void* const* d_in, const int* in_sizes, int n_in,
                              void* d_out, int out_size, void* d_ws, size_t ws_size,
                              hipStream_t stream) {
    const float* input  = (const float*)d_in[0];
    const float* weight = (const float*)d_in[1];
    const float* bias   = (const float*)d_in[2];
    float* out  = (float*)d_out;
    float* diag = (float*)d_ws;   // 4096 floats = 16 KiB scratch

    // 1) extract diagonal of weight into workspace (one-time, ~2 us)
    extract_diag_kernel<<<(NCOL + 255) / 256, 256, 0, stream>>>(weight, diag);

    // 2) vectorized elementwise scale + bias, column-fixed mapping
    const int block = 256;
    const int grid  = (NROW / ITERS) * QCOL / block;  // 512*1024/256 = 2048
    scale_bias_kernel<<<grid, block, 0, stream>>>(
        (const f4*)input, (const f4*)diag, (const f4*)bias,
        (f4*)out);
}

// Round 4
// 56.746 us; speedup vs baseline: 1.2256x; 1.2256x over previous
//
#include <hip/hip_runtime.h>

// Problem: out[r][c] = in[r][c] * weight[c][c] + bias[c]
// B = 8192 rows, N = 4096 cols, all float32.
// Pure memory-bound elementwise op: 128 MiB read + 128 MiB write.
//
// Thread t owns column-quad j = t & 1023 and rows r = (t >> 10) + 512*k,
// k = 0..15. diag/bias loop-invariant in registers; hot loop is
// 1 load + 1 store per 16 B.
// NOTE (round-3 lesson): __builtin_nontemporal_* REGRESSED 50.7->69.5 us
// on gfx950 — streaming loads/stores must stay on the normal cached path.

#define NCOL 4096
#define NROW 8192
#define QCOL (NCOL / 4)          // 1024 column quads
#define ROWGROUPS 512            // 524288 threads / 1024 quad-cols
#define ITERS (NROW / ROWGROUPS) // 16 rows per thread

typedef float f4 __attribute__((ext_vector_type(4)));

__global__ __launch_bounds__(256)
void extract_diag_kernel(const float* __restrict__ w, float* __restrict__ d) {
    int i = blockIdx.x * blockDim.x + threadIdx.x;
    if (i < NCOL) {
        d[i] = w[(size_t)i * (NCOL + 1)];   // w[i*N + i]
    }
}

__global__ __launch_bounds__(256)
void scale_bias_kernel(const f4* __restrict__ in,
                       const f4* __restrict__ diag4,
                       const f4* __restrict__ bias4,
                       f4* __restrict__ out) {
    const int t  = blockIdx.x * blockDim.x + threadIdx.x;  // 0..524287
    const int j  = t & (QCOL - 1);                         // fixed column quad
    const int r0 = t >> 10;                                // base row 0..511

    const f4 d = diag4[j];   // loop-invariant, cache-resident (16 KiB)
    const f4 b = bias4[j];

    size_t idx = (size_t)r0 * QCOL + j;
#pragma unroll
    for (int k = 0; k < ITERS; ++k) {
        f4 x = in[idx];
        f4 o;
        o.x = fmaf(x.x, d.x, b.x);
        o.y = fmaf(x.y, d.y, b.y);
        o.z = fmaf(x.z, d.z, b.z);
        o.w = fmaf(x.w, d.w, b.w);
        out[idx] = o;
        idx += (size_t)ROWGROUPS * QCOL;   // advance 512 rows
    }
}

extern "C" void kernel_launch(void* const* d_in, const int* in_sizes, int n_in,
                              void* d_out, int out_size, void* d_ws, size_t ws_size,
                              hipStream_t stream) {
    const float* input  = (const float*)d_in[0];
    const float* weight = (const float*)d_in[1];
    const float* bias   = (const float*)d_in[2];
    float* out  = (float*)d_out;
    float* diag = (float*)d_ws;   // 4096 floats = 16 KiB scratch

    // 1) extract diagonal of weight into workspace (one-time, ~2 us)
    extract_diag_kernel<<<(NCOL + 255) / 256, 256, 0, stream>>>(weight, diag);

    // 2) vectorized elementwise scale + bias, column-fixed mapping
    const int block = 256;
    const int grid  = (NROW / ITERS) * QCOL / block;  // 512*1024/256 = 2048
    scale_bias_kernel<<<grid, block, 0, stream>>>(
        (const f4*)input, (const f4*)diag, (const f4*)bias,
        (f4*)out);
}

// Round 5
// 53.055 us; speedup vs baseline: 1.3108x; 1.0696x over previous
//
#include <hip/hip_runtime.h>

// Problem: out[r][c] = in[r][c] * weight[c][c] + bias[c]
// B = 8192 rows, N = 4096 cols, all float32.
// Pure memory-bound: 128 MiB read + 128 MiB write. Floor ~43 us @ 6.3 TB/s.
//
// Lessons so far:
//  - R3: __builtin_nontemporal_* regressed 50.7->69.5 us (bypasses L2
//    aggregation on gfx950). Stay on cached path.
//  - R4: full 16x unroll regressed 50.7->56.7 us vs rolled grid-stride
//    (compiler batches unrolled loads/stores into long vmcnt groups,
//    killing request overlap). Keep the loop ROLLED.
//  - This round: fuse diag extraction (removes 2nd dispatch + ~4-6 us
//    serial gap). j = i & 1023 is invariant under the 524288 grid
//    stride, so diag/bias hoist to registers; diag scalars read
//    directly from weight (4096 lines, L2-resident after first touch).

#define NCOL 4096
#define NROW 8192
#define QCOL (NCOL / 4)   // 1024 column quads

typedef float f4 __attribute__((ext_vector_type(4)));

__global__ __launch_bounds__(256)
void scale_bias_kernel(const f4* __restrict__ in,
                       const float* __restrict__ w,
                       const f4* __restrict__ bias4,
                       f4* __restrict__ out,
                       long total4) {
    const int  t = blockIdx.x * blockDim.x + threadIdx.x;
    const int  j = t & (QCOL - 1);          // column quad, grid-stride-invariant
    const long stride = (long)gridDim.x * blockDim.x;

    // Diagonal scalars for columns 4j..4j+3, straight from weight.
    // Strided (64 KiB apart) but one-time per thread; 4096 distinct
    // lines total -> L2-broadcast after first touch.
    const size_t dstep = (size_t)NCOL + 1;
    f4 d;
    d.x = w[(size_t)(4 * j + 0) * dstep];
    d.y = w[(size_t)(4 * j + 1) * dstep];
    d.z = w[(size_t)(4 * j + 2) * dstep];
    d.w = w[(size_t)(4 * j + 3) * dstep];
    const f4 b = bias4[j];

    // Rolled grid-stride streaming loop: 1 load + 1 store per 16 B.
    for (long i = t; i < total4; i += stride) {
        f4 x = in[i];
        f4 o;
        o.x = fmaf(x.x, d.x, b.x);
        o.y = fmaf(x.y, d.y, b.y);
        o.z = fmaf(x.z, d.z, b.z);
        o.w = fmaf(x.w, d.w, b.w);
        out[i] = o;
    }
}

extern "C" void kernel_launch(void* const* d_in, const int* in_sizes, int n_in,
                              void* d_out, int out_size, void* d_ws, size_t ws_size,
                              hipStream_t stream) {
    const float* input  = (const float*)d_in[0];
    const float* weight = (const float*)d_in[1];
    const float* bias   = (const float*)d_in[2];
    float* out = (float*)d_out;

    const long total4 = (long)NROW * NCOL / 4;  // 8,388,608 float4s
    const int block = 256;
    const int grid  = 2048;  // 524288 threads; stride 524288 (mult of QCOL)
    scale_bias_kernel<<<grid, block, 0, stream>>>(
        (const f4*)input, weight, (const f4*)bias, (f4*)out, total4);
}